// Round 2
// baseline (94202.106 us; speedup 1.0000x reference)
//
#include <hip/hip_runtime.h>
#include <math.h>

#define TT 512
#define BB 128
#define IND 259
#define NNh 1024
#define NG 4096

// ---------------- fixed workspace (float elements) ----------------
#define WF_SZ   (259ull*4096)
#define ST_SZ   (128ull*1024)

__global__ __launch_bounds__(256) void k_zero(float* __restrict__ p, int n) {
    int i = blockIdx.x * 256 + threadIdx.x;
    int stride = gridDim.x * 256;
    for (; i < n; i += stride) p[i] = 0.f;
}

// WFOLD[i][j] = sum_e emb_W[i][e] * W0[e][j]   (i<259, e<512, j<4096)
__global__ __launch_bounds__(256) void k_fold(const float* __restrict__ embW,
                                              const float* __restrict__ W0,
                                              float* __restrict__ WF) {
    int j = blockIdx.x * 256 + threadIdx.x;
    int i = blockIdx.y;
    float acc = 0.f;
    for (int e = 0; e < 512; ++e)
        acc += embW[i * 512 + e] * W0[(size_t)e * NG + j];
    WF[(size_t)i * NG + j] = acc;
}

// S[j] = sum_{r=0..127} W0[512+r][j]  (the +/-1 "big" block collapses to sgn*S)
__global__ __launch_bounds__(256) void k_S(const float* __restrict__ W0, float* __restrict__ S) {
    int j = blockIdx.x * 256 + threadIdx.x;
    float acc = 0.f;
    for (int r = 0; r < 128; ++r)
        acc += W0[(size_t)(512 + r) * NG + j];
    S[j] = acc;
}

__global__ __launch_bounds__(256) void k_sgn(const float* __restrict__ inp, float* __restrict__ sgn) {
    int i = blockIdx.x * 256 + threadIdx.x;   // i = t*128+b, 65536 total
    float f0 = inp[(size_t)i * IND + 256];
    float f1 = inp[(size_t)i * IND + 257];
    sgn[i] = (f0 == 1.0f && f1 == 0.0f) ? 1.0f : -1.0f;
}

// Fused z = A1@W1 + A2@W2 + bias (+ sgn*S) followed by LSTM gate update.
// Tile: 32 rows x (8 hidden units x 4 gate strips = 32 z-cols). Each wg owns
// disjoint (row, hidden) pairs so c_state RMW is race-free; h ping-pongs.
#define KT 32
#define MT 32
#define HT 8
#define CT 32
__global__ __launch_bounds__(256) void k_cell(
    const float* __restrict__ A1, int lda1, int KA,
    const float* __restrict__ W1,
    const float* __restrict__ A2,
    const float* __restrict__ W2,
    const float* __restrict__ bias,
    const float* __restrict__ Svec,
    const float* __restrict__ sgn,
    float* __restrict__ c_state,
    float* __restrict__ h_out)
{
    __shared__ float As[KT][MT + 4];
    __shared__ float Ws[KT][CT + 4];
    __shared__ float zs[MT][CT + 1];

    const int tid = threadIdx.x;
    const int m0  = blockIdx.y * MT;
    const int hh0 = blockIdx.x * HT;
    const int tr  = tid >> 4;   // 0..15 -> rows 2*tr, 2*tr+1
    const int tc  = tid & 15;   // cols 2*tc, 2*tc+1

    float acc00 = 0.f, acc01 = 0.f, acc10 = 0.f, acc11 = 0.f;

    for (int phase = 0; phase < 2; ++phase) {
        const float* __restrict__ A = phase ? A2 : A1;
        const float* __restrict__ W = phase ? W2 : W1;
        const int lda = phase ? 1024 : lda1;
        const int K   = phase ? 1024 : KA;
        for (int kt = 0; kt < K; kt += KT) {
            // stage A transposed: As[k][r] = A[m0+r][kt+k]
            {
                int r  = tid >> 3;            // 0..31
                int k4 = (tid & 7) << 2;      // 0..28
                int kg = kt + k4;
                const float* ap = &A[(size_t)(m0 + r) * lda + kg];
                float4 v;
                if (((lda & 3) == 0) && (kg + 3 < K)) {
                    v = *reinterpret_cast<const float4*>(ap);
                } else {
                    v.x = (kg + 0 < K) ? ap[0] : 0.f;
                    v.y = (kg + 1 < K) ? ap[1] : 0.f;
                    v.z = (kg + 2 < K) ? ap[2] : 0.f;
                    v.w = (kg + 3 < K) ? ap[3] : 0.f;
                }
                As[k4 + 0][r] = v.x; As[k4 + 1][r] = v.y;
                As[k4 + 2][r] = v.z; As[k4 + 3][r] = v.w;
            }
            // stage W: Ws[k][c] with col j = (c>>3)*1024 + hh0 + (c&7)
            {
                int k  = tid >> 3;            // 0..31
                int s  = (tid & 7) >> 1;      // gate strip 0..3
                int q  = tid & 1;             // half of 8 cols
                int kg = kt + k;
                float4 v = make_float4(0.f, 0.f, 0.f, 0.f);
                if (kg < K)
                    v = *reinterpret_cast<const float4*>(&W[(size_t)kg * NG + s * NNh + hh0 + q * 4]);
                int c = s * 8 + q * 4;
                Ws[k][c + 0] = v.x; Ws[k][c + 1] = v.y;
                Ws[k][c + 2] = v.z; Ws[k][c + 3] = v.w;
            }
            __syncthreads();
            #pragma unroll
            for (int k = 0; k < KT; ++k) {
                float a0 = As[k][tr * 2 + 0];
                float a1 = As[k][tr * 2 + 1];
                float w0 = Ws[k][tc * 2 + 0];
                float w1 = Ws[k][tc * 2 + 1];
                acc00 += a0 * w0; acc01 += a0 * w1;
                acc10 += a1 * w0; acc11 += a1 * w1;
            }
            __syncthreads();
        }
    }

    // epilogue: bias (+ sgn*S), park z in LDS
    float s0 = 0.f, s1 = 0.f;
    if (sgn) { s0 = sgn[m0 + tr * 2 + 0]; s1 = sgn[m0 + tr * 2 + 1]; }
    #pragma unroll
    for (int q = 0; q < 2; ++q) {
        int c = tc * 2 + q;
        int jcol = (c >> 3) * NNh + hh0 + (c & 7);
        float bb = bias[jcol];
        float sv = Svec ? Svec[jcol] : 0.f;
        float z0 = (q == 0 ? acc00 : acc01) + bb + s0 * sv;
        float z1 = (q == 0 ? acc10 : acc11) + bb + s1 * sv;
        zs[tr * 2 + 0][c] = z0;
        zs[tr * 2 + 1][c] = z1;
    }
    __syncthreads();

    // gate combine: one (row, hidden) pair per thread
    {
        int r  = tid >> 3;   // 0..31
        int hh = tid & 7;    // 0..7
        float zf = zs[r][hh];
        float zi = zs[r][8 + hh];
        float zo = zs[r][16 + hh];
        float zg = zs[r][24 + hh];
        float fg = 1.f / (1.f + expf(-zf));
        float ig = 1.f / (1.f + expf(-zi));
        float og = 1.f / (1.f + expf(-zo));
        float gg = tanhf(zg);
        size_t idx = (size_t)(m0 + r) * NNh + hh0 + hh;
        float cn = fg * c_state[idx] + ig * gg;
        c_state[idx] = cn;
        h_out[idx] = og * tanhf(cn);
    }
}

// Fused output head: per wg 16 rows; hs (16x1024) lives in LDS; no HS buffer.
// H1chunk holds `rows` consecutive (t,b) rows; out points at matching offset.
__global__ __launch_bounds__(256) void k_head(
    const float* __restrict__ H1chunk,
    const float* __restrict__ W0, const float* __restrict__ b0,
    const float* __restrict__ W1, const float* __restrict__ b1,
    float* __restrict__ out)
{
    __shared__ float sA[16 * 1024];
    const int tid = threadIdx.x;
    const size_t m0 = (size_t)blockIdx.x * 16;

    const float* Ablk = H1chunk + m0 * 1024;
    for (int idx = tid * 4; idx < 16 * 1024; idx += 256 * 4)
        *reinterpret_cast<float4*>(&sA[idx]) = *reinterpret_cast<const float4*>(&Ablk[idx]);
    __syncthreads();

    // phase 1: hs = relu(A @ W0 + b0); each thread owns 4 contiguous cols
    float acc[4][16];
    #pragma unroll
    for (int j = 0; j < 4; ++j)
        #pragma unroll
        for (int r = 0; r < 16; ++r) acc[j][r] = 0.f;

    const int c0 = tid * 4;
    for (int k = 0; k < 1024; ++k) {
        float4 wv = *reinterpret_cast<const float4*>(&W0[(size_t)k * 1024 + c0]);
        #pragma unroll
        for (int r = 0; r < 16; ++r) {
            float a = sA[r * 1024 + k];
            acc[0][r] += a * wv.x;
            acc[1][r] += a * wv.y;
            acc[2][r] += a * wv.z;
            acc[3][r] += a * wv.w;
        }
    }
    __syncthreads();
    {
        float4 bv = *reinterpret_cast<const float4*>(&b0[c0]);
        #pragma unroll
        for (int r = 0; r < 16; ++r) {
            float4 h;
            h.x = fmaxf(acc[0][r] + bv.x, 0.f);
            h.y = fmaxf(acc[1][r] + bv.y, 0.f);
            h.z = fmaxf(acc[2][r] + bv.z, 0.f);
            h.w = fmaxf(acc[3][r] + bv.w, 0.f);
            *reinterpret_cast<float4*>(&sA[r * 1024 + c0]) = h;
        }
    }
    __syncthreads();

    // phase 2: logits = hs @ W1 + b1; thread = vocab column
    float acc2[16];
    #pragma unroll
    for (int r = 0; r < 16; ++r) acc2[r] = 0.f;
    for (int k = 0; k < 1024; ++k) {
        float wv = W1[(size_t)k * 256 + tid];
        #pragma unroll
        for (int r = 0; r < 16; ++r)
            acc2[r] += sA[r * 1024 + k] * wv;
    }
    float bb = b1[tid];
    #pragma unroll
    for (int r = 0; r < 16; ++r)
        out[(m0 + r) * 256 + tid] = acc2[r] + bb;
}

extern "C" void kernel_launch(void* const* d_in, const int* in_sizes, int n_in,
                              void* d_out, int out_size, void* d_ws, size_t ws_size,
                              hipStream_t stream)
{
    (void)in_sizes; (void)n_in; (void)out_size;
    const float* inputs = (const float*)d_in[0];
    const float* embW   = (const float*)d_in[1];
    const float* W0     = (const float*)d_in[2];
    const float* b0     = (const float*)d_in[3];
    const float* W1     = (const float*)d_in[4];
    const float* b1     = (const float*)d_in[5];
    const float* oW0    = (const float*)d_in[6];
    const float* ob0    = (const float*)d_in[7];
    const float* oW1    = (const float*)d_in[8];
    const float* ob1    = (const float*)d_in[9];
    float* out = (float*)d_out;
    float* w   = (float*)d_ws;

    // ---- adaptive workspace layout (never exceed ws_size) ----
    float* WF  = w;                     // 259*4096
    float* Sv  = WF  + WF_SZ;           // 4096
    float* SG  = Sv  + 4096;            // 512*128
    float* h0a = SG  + (size_t)TT * BB; // 128*1024 each below
    float* h0b = h0a + ST_SZ;
    float* c0  = h0b + ST_SZ;
    float* c1  = c0  + ST_SZ;
    float* zr  = c1  + ST_SZ;
    float* H1  = zr  + ST_SZ;           // ring buffer, R*128*1024 floats

    size_t fixed_floats = (size_t)(H1 - w);
    size_t avail_floats = ws_size / sizeof(float);
    size_t ring_avail   = (avail_floats > fixed_floats) ? (avail_floats - fixed_floats) : 0;

    int R = 512;                        // ring steps: power-of-2 divisor of 512
    while (R > 1 && (size_t)R * BB * NNh > ring_avail) R >>= 1;

    // zero h0a,h0b,c0,c1,zr (contiguous block of 5*ST_SZ floats)
    k_zero<<<64, 256, 0, stream>>>(h0a, (int)(5 * ST_SZ));
    k_fold<<<dim3(16, 259), 256, 0, stream>>>(embW, W0, WF);
    k_S<<<16, 256, 0, stream>>>(W0, Sv);
    k_sgn<<<256, 256, 0, stream>>>(inputs, SG);

    for (int t = 0; t < TT; ++t) {
        float* h0_prev = (t & 1) ? h0b : h0a;
        float* h0_new  = (t & 1) ? h0a : h0b;
        const float* h1_prev = (t == 0) ? zr : (H1 + (size_t)((t - 1) % R) * BB * NNh);
        float* h1_new = H1 + (size_t)(t % R) * BB * NNh;

        // cell 0: z0 = inp_t @ WFOLD + sgn*S + h0 @ W0[640:] + b0
        k_cell<<<dim3(128, 4), 256, 0, stream>>>(
            inputs + (size_t)t * BB * IND, IND, IND, WF,
            h0_prev, W0 + (size_t)640 * NG,
            b0, Sv, SG + (size_t)t * BB,
            c0, h0_new);
        // cell 1: z1 = h0_new @ W1[:1024] + h1_prev @ W1[1024:] + b1
        k_cell<<<dim3(128, 4), 256, 0, stream>>>(
            h0_new, 1024, 1024, W1,
            h1_prev, W1 + (size_t)1024 * NG,
            b1, nullptr, nullptr,
            c1, h1_new);

        // head on each completed ring chunk (stream order => race-free)
        if ((t + 1) % R == 0) {
            int chunk_first_t = t + 1 - R;
            k_head<<<R * BB / 16, 256, 0, stream>>>(
                H1, oW0, ob0, oW1, ob1,
                out + (size_t)chunk_first_t * BB * 256);
        }
    }
}

// Round 3
// 23853.836 us; speedup vs baseline: 3.9491x; 3.9491x over previous
//
#include <hip/hip_runtime.h>
#include <hip/hip_bf16.h>
#include <math.h>

typedef unsigned short u16;
typedef short short8v __attribute__((ext_vector_type(8)));
typedef float f32x4 __attribute__((ext_vector_type(4)));

#define TT 512
#define BB 128
#define IND 259
#define KPWF 320

// LDS layout (bytes): per buffer: A_hi[128][80] A_lo[128][80] B_hi[64][80] B_lo[64][80]
#define LA_LO 10240
#define LB_HI 20480
#define LB_LO 25600
#define LBUF  30720
#define LDS_BYTES (2*LBUF)

__device__ __forceinline__ u16 f2bf(float x) {
    __hip_bfloat16 h = __float2bfloat16(x);
    return *reinterpret_cast<u16*>(&h);
}
__device__ __forceinline__ float bf2f(u16 u) {
    unsigned v = ((unsigned)u) << 16;
    return __uint_as_float(v);
}
__device__ __forceinline__ void splitbf(float x, u16& hi, u16& lo) {
    hi = f2bf(x);
    lo = f2bf(x - bf2f(hi));
}

// ---------------- small prep kernels ----------------
__global__ __launch_bounds__(256) void k_zero(float* __restrict__ p, int n) {
    int i = blockIdx.x * 256 + threadIdx.x;
    int stride = gridDim.x * 256;
    for (; i < n; i += stride) p[i] = 0.f;
}

// WFOLD[i][j] = sum_e emb_W[i][e] * W0[e][j]   (i<259, e<512, j<4096)
__global__ __launch_bounds__(256) void k_fold(const float* __restrict__ embW,
                                              const float* __restrict__ W0,
                                              float* __restrict__ WF) {
    int j = blockIdx.x * 256 + threadIdx.x;
    int i = blockIdx.y;
    float acc = 0.f;
    for (int e = 0; e < 512; ++e)
        acc += embW[i * 512 + e] * W0[(size_t)e * 4096 + j];
    WF[(size_t)i * 4096 + j] = acc;
}

__global__ __launch_bounds__(256) void k_S(const float* __restrict__ W0, float* __restrict__ S) {
    int j = blockIdx.x * 256 + threadIdx.x;
    float acc = 0.f;
    for (int r = 0; r < 128; ++r)
        acc += W0[(size_t)(512 + r) * 4096 + j];
    S[j] = acc;
}

__global__ __launch_bounds__(256) void k_sgn(const float* __restrict__ inp, float* __restrict__ sgn) {
    int i = blockIdx.x * 256 + threadIdx.x;
    float f0 = inp[(size_t)i * IND + 256];
    float f1 = inp[(size_t)i * IND + 257];
    sgn[i] = (f0 == 1.0f && f1 == 0.0f) ? 1.0f : -1.0f;
}

// Transpose + bf16 hi/lo split (+ optional gate-permute of columns).
// dst[col'][k] = src[k][j(col')], col' = hs*64 + g*16 + c  <->  j = g*1024 + hs*16 + c
__global__ __launch_bounds__(256) void k_split(const float* __restrict__ src, int srcStride,
                                               int K, int Kpad, int perm,
                                               u16* __restrict__ hi, u16* __restrict__ lo) {
    int col = blockIdx.y;
    int k = blockIdx.x * 256 + threadIdx.x;
    if (k >= Kpad) return;
    int j = col;
    if (perm) {
        int c = col & 15, g = (col >> 4) & 3, hs = col >> 6;
        j = g * 1024 + hs * 16 + c;
    }
    float v = (k < K) ? src[(size_t)k * srcStride + j] : 0.f;
    u16 h, l; splitbf(v, h, l);
    hi[(size_t)col * Kpad + k] = h;
    lo[(size_t)col * Kpad + k] = l;
}

// ---------------- split-bf16 MFMA GEMM core ----------------
// Tile: 128 rows x NC cols, 4 waves as 2x2 (wave = 64 x NC/2), 16x16x32 frags.
// K processed in 32-wide tiles, double-buffered LDS, reg-staged.
template<int NC, int AMODE>
__device__ __forceinline__ void gemm_core(
    char* smem, int tid,
    const u16* Ah0, const u16* Al0,      // AMODE0: bf16 hi/lo A, lda=1024 elements
    const u16* Ah1, const u16* Al1,      // phase-1 A (cell1), used for kt >= phsw
    int phsw,
    const float* Af,                     // AMODE1: fp32 A, lda=IND, guard k<IND
    const u16* Bh, const u16* Bl, int ldb,
    int bmode, int bhalf,                // bmode1: gate-chunk col map (8-col chunks)
    int nkt,
    f32x4 (&acc)[4][NC/32])
{
    const int lane = tid & 63, wid = tid >> 6;
    const int wr = (wid >> 1) * 64;
    const int wc = (wid & 1) * (NC / 2);
    const int rlo = lane & 15, khi = lane >> 4;

    const int srow = tid >> 1, shalf = tid & 1;
    int bc, bu;
    if (NC == 64) { bc = tid >> 2; bu = tid & 3; }
    else          { bc = tid >> 3; bu = tid & 7; }
    int bcg = bc;
    if (bmode) bcg = ((bc >> 3) * 16) + bhalf * 8 + (bc & 7);

    uint4 rah0, rah1, ral0, ral1, rbh0, rbl0;
    float raf[16];

    auto LOADF = [&](int kt) {
        int k0 = kt * 32;
        if (AMODE == 0) {
            const u16* pAh = Ah0; const u16* pAl = Al0; int kk = k0;
            if (kt >= phsw) { pAh = Ah1; pAl = Al1; kk = (kt - phsw) * 32; }
            const u16* sa = pAh + (size_t)srow * 1024 + kk + shalf * 16;
            rah0 = *(const uint4*)(sa);
            rah1 = *(const uint4*)(sa + 8);
            const u16* sb = pAl + (size_t)srow * 1024 + kk + shalf * 16;
            ral0 = *(const uint4*)(sb);
            ral1 = *(const uint4*)(sb + 8);
        } else {
            const float* sa = Af + (size_t)srow * IND;
            #pragma unroll
            for (int j = 0; j < 16; ++j) {
                int kk = k0 + shalf * 16 + j;
                raf[j] = (kk < IND) ? sa[kk] : 0.f;
            }
        }
        if (NC == 64) {
            rbh0 = *(const uint4*)(Bh + (size_t)bcg * ldb + k0 + bu * 8);
            rbl0 = *(const uint4*)(Bl + (size_t)bcg * ldb + k0 + bu * 8);
        } else {
            const u16* basep = (bu < 4 ? Bh : Bl);
            rbh0 = *(const uint4*)(basep + (size_t)bcg * ldb + k0 + (bu & 3) * 8);
        }
    };
    auto WRITEF = [&](int kt) {
        char* b = smem + (kt & 1) * LBUF;
        char* d = b + srow * 80 + shalf * 32;
        if (AMODE == 0) {
            *(uint4*)(d) = rah0; *(uint4*)(d + 16) = rah1;
            *(uint4*)(d + LA_LO) = ral0; *(uint4*)(d + LA_LO + 16) = ral1;
        } else {
            alignas(16) u16 hb[16]; alignas(16) u16 lb[16];
            #pragma unroll
            for (int j = 0; j < 16; ++j) splitbf(raf[j], hb[j], lb[j]);
            *(uint4*)(d) = *(uint4*)&hb[0]; *(uint4*)(d + 16) = *(uint4*)&hb[8];
            *(uint4*)(d + LA_LO) = *(uint4*)&lb[0]; *(uint4*)(d + LA_LO + 16) = *(uint4*)&lb[8];
        }
        if (NC == 64) {
            char* e = b + LB_HI + bc * 80 + bu * 16;
            *(uint4*)(e) = rbh0;
            *(uint4*)(e + (LB_LO - LB_HI)) = rbl0;
        } else {
            char* e = b + (bu < 4 ? LB_HI : LB_LO) + bc * 80 + (bu & 3) * 16;
            *(uint4*)(e) = rbh0;
        }
    };
    auto COMPUTEF = [&](int kt) {
        const char* b = smem + (kt & 1) * LBUF;
        short8v ah[4], al[4], bh[NC/32], bl[NC/32];
        #pragma unroll
        for (int rf = 0; rf < 4; ++rf) {
            int arow = wr + rf * 16 + rlo;
            const char* p = b + arow * 80 + khi * 16;
            ah[rf] = *(const short8v*)(p);
            al[rf] = *(const short8v*)(p + LA_LO);
        }
        #pragma unroll
        for (int cf = 0; cf < NC/32; ++cf) {
            int bcol = wc + cf * 16 + rlo;
            const char* p = b + LB_HI + bcol * 80 + khi * 16;
            bh[cf] = *(const short8v*)(p);
            bl[cf] = *(const short8v*)(p + (LB_LO - LB_HI));
        }
        #pragma unroll
        for (int rf = 0; rf < 4; ++rf)
            #pragma unroll
            for (int cf = 0; cf < NC/32; ++cf) {
                acc[rf][cf] = __builtin_amdgcn_mfma_f32_16x16x32_bf16(ah[rf], bh[cf], acc[rf][cf], 0, 0, 0);
                acc[rf][cf] = __builtin_amdgcn_mfma_f32_16x16x32_bf16(ah[rf], bl[cf], acc[rf][cf], 0, 0, 0);
                acc[rf][cf] = __builtin_amdgcn_mfma_f32_16x16x32_bf16(al[rf], bh[cf], acc[rf][cf], 0, 0, 0);
            }
    };

    LOADF(0); WRITEF(0); __syncthreads();
    for (int kt = 0; kt < nkt; ++kt) {
        if (kt + 1 < nkt) LOADF(kt + 1);
        COMPUTEF(kt);
        if (kt + 1 < nkt) WRITEF(kt + 1);
        __syncthreads();
    }
}

template<int NC>
__device__ __forceinline__ void store_zs(char* smem, int tid, f32x4 (&acc)[4][NC/32], int ncp) {
    float* zs = (float*)smem;
    const int lane = tid & 63, wid = tid >> 6;
    const int wr = (wid >> 1) * 64;
    const int wc = (wid & 1) * (NC / 2);
    const int rlo = lane & 15, khi = lane >> 4;
    #pragma unroll
    for (int rf = 0; rf < 4; ++rf)
        #pragma unroll
        for (int cf = 0; cf < NC/32; ++cf)
            #pragma unroll
            for (int r = 0; r < 4; ++r)
                zs[(wr + rf*16 + khi*4 + r) * ncp + wc + cf*16 + rlo] = acc[rf][cf][r];
}

// ---------------- merged per-step kernel ----------------
struct SArgs {
    const float *inp, *Sv, *SG, *b0, *b1;
    const u16 *WFh, *WFl, *W0h, *W0l, *W1h, *W1l;
    u16 *h0h0, *h0l0, *h0h1, *h0l1;
    u16 *ringh, *ringl;
    float *Zin, *c0, *c1;
    int R, t;
};

__global__ __launch_bounds__(256) void k_step(SArgs a) {
    extern __shared__ char smem[];
    const int bid = blockIdx.x, tid = threadIdx.x;
    const int t = a.t;

    if (bid < 64) {
        // ---------- cell0 step t:  z = h0[t-1] @ W0h + Zin[t] + sgn*S + b0 ----------
        if (t < 0 || t >= TT) return;
        const int hs = bid;
        f32x4 acc[4][2];
        #pragma unroll
        for (int i = 0; i < 4; ++i) { acc[i][0] = (f32x4)0.f; acc[i][1] = (f32x4)0.f; }
        const u16* Ah = (((t - 1) & 1) ? a.h0h1 : a.h0h0);
        const u16* Al = (((t - 1) & 1) ? a.h0l1 : a.h0l0);
        gemm_core<64,0>(smem, tid, Ah, Al, Ah, Al, 32, nullptr,
                        a.W0h + (size_t)hs*64*1024, a.W0l + (size_t)hs*64*1024, 1024,
                        0, 0, 32, acc);
        store_zs<64>(smem, tid, acc, 68);
        __syncthreads();
        float* zs = (float*)smem;
        const float* zin = a.Zin + (size_t)(t & 1) * BB * 4096;
        u16* hoh = ((t & 1) ? a.h0h1 : a.h0h0);
        u16* hol = ((t & 1) ? a.h0l1 : a.h0l0);
        #pragma unroll
        for (int i = 0; i < 8; ++i) {
            int q = tid + 256 * i;
            int row = q >> 4, c16 = q & 15;
            int hid = hs * 16 + c16;
            float sg = a.SG[(size_t)t * BB + row];
            const float* zr = zs + row * 68;
            const float* zn = zin + (size_t)row * 4096 + hs * 64;
            float zF = zr[c16]      + zn[c16]      + sg * a.Sv[hid]        + a.b0[hid];
            float zI = zr[16 + c16] + zn[16 + c16] + sg * a.Sv[1024 + hid] + a.b0[1024 + hid];
            float zO = zr[32 + c16] + zn[32 + c16] + sg * a.Sv[2048 + hid] + a.b0[2048 + hid];
            float zG = zr[48 + c16] + zn[48 + c16] + sg * a.Sv[3072 + hid] + a.b0[3072 + hid];
            float f = 1.f / (1.f + expf(-zF));
            float ii = 1.f / (1.f + expf(-zI));
            float o = 1.f / (1.f + expf(-zO));
            float g = tanhf(zG);
            size_t ci = (size_t)row * 1024 + hid;
            float cn = f * a.c0[ci] + ii * g;
            a.c0[ci] = cn;
            float h = o * tanhf(cn);
            u16 hh, hl; splitbf(h, hh, hl);
            hoh[ci] = hh; hol[ci] = hl;
        }
    } else if (bid < 192) {
        // ---------- cell1 step tau=t-1: z = [h0[tau], h1[tau-1]] @ W1 + b1 ----------
        const int tau = t - 1;
        if (tau < 0 || tau >= TT) return;
        const int bb = bid - 64;
        const int hs = bb >> 1, half = bb & 1;
        f32x4 acc[4][1];
        #pragma unroll
        for (int i = 0; i < 4; ++i) acc[i][0] = (f32x4)0.f;
        const u16* A0h = ((tau & 1) ? a.h0h1 : a.h0h0);
        const u16* A0l = ((tau & 1) ? a.h0l1 : a.h0l0);
        int slotr = (tau - 1 + a.R) % a.R;
        const u16* A1h = a.ringh + (size_t)slotr * BB * 1024;
        const u16* A1l = a.ringl + (size_t)slotr * BB * 1024;
        gemm_core<32,0>(smem, tid, A0h, A0l, A1h, A1l, 32, nullptr,
                        a.W1h + (size_t)hs*64*2048, a.W1l + (size_t)hs*64*2048, 2048,
                        1, half, 64, acc);
        store_zs<32>(smem, tid, acc, 36);
        __syncthreads();
        float* zs = (float*)smem;
        int slotw = tau % a.R;
        u16* rh = a.ringh + (size_t)slotw * BB * 1024;
        u16* rl = a.ringl + (size_t)slotw * BB * 1024;
        #pragma unroll
        for (int i = 0; i < 4; ++i) {
            int q = tid + 256 * i;
            int row = q >> 3, c8 = q & 7;
            int hid = hs * 16 + half * 8 + c8;
            const float* zr = zs + row * 36;
            float zF = zr[c8]      + a.b1[hid];
            float zI = zr[8 + c8]  + a.b1[1024 + hid];
            float zO = zr[16 + c8] + a.b1[2048 + hid];
            float zG = zr[24 + c8] + a.b1[3072 + hid];
            float f = 1.f / (1.f + expf(-zF));
            float ii = 1.f / (1.f + expf(-zI));
            float o = 1.f / (1.f + expf(-zO));
            float g = tanhf(zG);
            size_t ci = (size_t)row * 1024 + hid;
            float cn = f * a.c1[ci] + ii * g;
            a.c1[ci] = cn;
            float h = o * tanhf(cn);
            u16 hh, hl; splitbf(h, hh, hl);
            rh[ci] = hh; rl[ci] = hl;
        }
    } else {
        // ---------- Zin for step t+1:  Zin = inp[t+1] @ WFt ----------
        const int tz = t + 1;
        if (tz < 0 || tz >= TT) return;
        const int cwg = bid - 192;       // 64 wgs x 64 cols
        const int col0 = cwg * 64;
        f32x4 acc[4][2];
        #pragma unroll
        for (int i = 0; i < 4; ++i) { acc[i][0] = (f32x4)0.f; acc[i][1] = (f32x4)0.f; }
        const float* Af = a.inp + (size_t)tz * BB * IND;
        gemm_core<64,1>(smem, tid, nullptr, nullptr, nullptr, nullptr, 99, Af,
                        a.WFh + (size_t)col0 * KPWF, a.WFl + (size_t)col0 * KPWF, KPWF,
                        0, 0, KPWF / 32, acc);
        float* zo = a.Zin + (size_t)(tz & 1) * BB * 4096;
        const int lane = tid & 63, wid = tid >> 6;
        const int wr = (wid >> 1) * 64, wc = (wid & 1) * 32;
        const int rlo = lane & 15, khi = lane >> 4;
        #pragma unroll
        for (int rf = 0; rf < 4; ++rf)
            #pragma unroll
            for (int cf = 0; cf < 2; ++cf)
                #pragma unroll
                for (int r = 0; r < 4; ++r)
                    zo[(size_t)(wr + rf*16 + khi*4 + r) * 4096 + col0 + wc + cf*16 + rlo] = acc[rf][cf][r];
    }
}

// ---------------- head: hs = relu(H1 @ oW0 + b0); logits = hs @ oW1 + b1 ----------------
__global__ __launch_bounds__(256) void k_head1(const u16* __restrict__ ringh, const u16* __restrict__ ringl,
                                               const u16* __restrict__ Wh, const u16* __restrict__ Wl,
                                               const float* __restrict__ bias,
                                               u16* __restrict__ hsh, u16* __restrict__ hsl) {
    extern __shared__ char smem[];
    const int tid = threadIdx.x;
    const int m = blockIdx.x >> 4, nb = blockIdx.x & 15;
    f32x4 acc[4][2];
    #pragma unroll
    for (int i = 0; i < 4; ++i) { acc[i][0] = (f32x4)0.f; acc[i][1] = (f32x4)0.f; }
    const u16* Ah = ringh + (size_t)m * BB * 1024;
    const u16* Al = ringl + (size_t)m * BB * 1024;
    gemm_core<64,0>(smem, tid, Ah, Al, Ah, Al, 99, nullptr,
                    Wh + (size_t)nb*64*1024, Wl + (size_t)nb*64*1024, 1024,
                    0, 0, 32, acc);
    const int lane = tid & 63, wid = tid >> 6;
    const int wr = (wid >> 1) * 64, wc = (wid & 1) * 32;
    const int rlo = lane & 15, khi = lane >> 4;
    #pragma unroll
    for (int rf = 0; rf < 4; ++rf)
        #pragma unroll
        for (int cf = 0; cf < 2; ++cf)
            #pragma unroll
            for (int r = 0; r < 4; ++r) {
                int row = wr + rf*16 + khi*4 + r;
                int col = nb*64 + wc + cf*16 + rlo;
                float v = acc[rf][cf][r] + bias[col];
                v = fmaxf(v, 0.f);
                u16 hh, hl; splitbf(v, hh, hl);
                size_t o = (size_t)(m * BB + row) * 1024 + col;
                hsh[o] = hh; hsl[o] = hl;
            }
}

__global__ __launch_bounds__(256) void k_head2(const u16* __restrict__ hsh, const u16* __restrict__ hsl,
                                               const u16* __restrict__ Wh, const u16* __restrict__ Wl,
                                               const float* __restrict__ bias,
                                               float* __restrict__ outp) {
    extern __shared__ char smem[];
    const int tid = threadIdx.x;
    const int m = blockIdx.x >> 2, nb = blockIdx.x & 3;
    f32x4 acc[4][2];
    #pragma unroll
    for (int i = 0; i < 4; ++i) { acc[i][0] = (f32x4)0.f; acc[i][1] = (f32x4)0.f; }
    const u16* Ah = hsh + (size_t)m * BB * 1024;
    const u16* Al = hsl + (size_t)m * BB * 1024;
    gemm_core<64,0>(smem, tid, Ah, Al, Ah, Al, 99, nullptr,
                    Wh + (size_t)nb*64*1024, Wl + (size_t)nb*64*1024, 1024,
                    0, 0, 32, acc);
    const int lane = tid & 63, wid = tid >> 6;
    const int wr = (wid >> 1) * 64, wc = (wid & 1) * 32;
    const int rlo = lane & 15, khi = lane >> 4;
    #pragma unroll
    for (int rf = 0; rf < 4; ++rf)
        #pragma unroll
        for (int cf = 0; cf < 2; ++cf)
            #pragma unroll
            for (int r = 0; r < 4; ++r) {
                int row = wr + rf*16 + khi*4 + r;
                int col = nb*64 + wc + cf*16 + rlo;
                outp[(size_t)(m * BB + row) * 256 + col] = acc[rf][cf][r] + bias[col];
            }
}

// ---------------- host ----------------
extern "C" void kernel_launch(void* const* d_in, const int* in_sizes, int n_in,
                              void* d_out, int out_size, void* d_ws, size_t ws_size,
                              hipStream_t stream)
{
    (void)in_sizes; (void)n_in; (void)out_size;
    const float* inputs = (const float*)d_in[0];
    const float* embW   = (const float*)d_in[1];
    const float* W0     = (const float*)d_in[2];
    const float* b0     = (const float*)d_in[3];
    const float* W1     = (const float*)d_in[4];
    const float* b1     = (const float*)d_in[5];
    const float* oW0    = (const float*)d_in[6];
    const float* ob0    = (const float*)d_in[7];
    const float* oW1    = (const float*)d_in[8];
    const float* ob1    = (const float*)d_in[9];
    float* out = (float*)d_out;

    char* base = (char*)d_ws;
    size_t off = 0;
    auto take = [&](size_t n) -> char* {
        size_t a = (off + 255) & ~(size_t)255;
        char* r = base + a;
        off = a + n;
        return r;
    };

    u16* WFh = (u16*)take(4096ull * KPWF * 2);
    u16* WFl = (u16*)take(4096ull * KPWF * 2);
    u16* W0h = (u16*)take(4096ull * 1024 * 2);
    u16* W0l = (u16*)take(4096ull * 1024 * 2);
    u16* W1h = (u16*)take(4096ull * 2048 * 2);
    u16* W1l = (u16*)take(4096ull * 2048 * 2);
    u16* oWAh = (u16*)take(1024ull * 1024 * 2);
    u16* oWAl = (u16*)take(1024ull * 1024 * 2);
    u16* oWBh = (u16*)take(256ull * 1024 * 2);
    u16* oWBl = (u16*)take(256ull * 1024 * 2);
    float* WFfold = (float*)take(259ull * 4096 * 4);
    float* Sv = (float*)take(4096 * 4);
    float* SG = (float*)take((size_t)TT * BB * 4);
    float* Zin = (float*)take(2ull * BB * 4096 * 4);
    u16* h0h0 = (u16*)take((size_t)BB * 1024 * 2);
    u16* h0l0 = (u16*)take((size_t)BB * 1024 * 2);
    u16* h0h1 = (u16*)take((size_t)BB * 1024 * 2);
    u16* h0l1 = (u16*)take((size_t)BB * 1024 * 2);
    float* c0 = (float*)take((size_t)BB * 1024 * 4);
    float* c1 = (float*)take((size_t)BB * 1024 * 4);

    size_t avail = (ws_size > off + (1u << 20)) ? (ws_size - off - (1u << 20)) : 0;
    int R = 512;
    while (R > 2 && (size_t)R * (BB * 1024ull * 2 * 4) > avail) R >>= 1;
    u16* ringh = (u16*)take((size_t)R * BB * 1024 * 2);
    u16* ringl = (u16*)take((size_t)R * BB * 1024 * 2);
    u16* hsh   = (u16*)take((size_t)R * BB * 1024 * 2);
    u16* hsl   = (u16*)take((size_t)R * BB * 1024 * 2);

    // -------- prep --------
    k_fold<<<dim3(16, 259), 256, 0, stream>>>(embW, W0, WFfold);
    k_S<<<16, 256, 0, stream>>>(W0, Sv);
    k_sgn<<<256, 256, 0, stream>>>(inputs, SG);
    k_split<<<dim3(2, 4096), 256, 0, stream>>>(WFfold, 4096, 259, KPWF, 1, WFh, WFl);
    k_split<<<dim3(4, 4096), 256, 0, stream>>>(W0 + 640ull * 4096, 4096, 1024, 1024, 1, W0h, W0l);
    k_split<<<dim3(8, 4096), 256, 0, stream>>>(W1, 4096, 2048, 2048, 1, W1h, W1l);
    k_split<<<dim3(4, 1024), 256, 0, stream>>>(oW0, 1024, 1024, 1024, 0, oWAh, oWAl);
    k_split<<<dim3(4, 256), 256, 0, stream>>>(oW1, 256, 1024, 1024, 0, oWBh, oWBl);
    k_zero<<<64, 256, 0, stream>>>(c0, BB * 1024);
    k_zero<<<64, 256, 0, stream>>>(c1, BB * 1024);
    k_zero<<<32, 256, 0, stream>>>((float*)h0h1, BB * 1024 / 2);
    k_zero<<<32, 256, 0, stream>>>((float*)h0l1, BB * 1024 / 2);
    k_zero<<<32, 256, 0, stream>>>((float*)(ringh + (size_t)(R - 1) * BB * 1024), BB * 1024 / 2);
    k_zero<<<32, 256, 0, stream>>>((float*)(ringl + (size_t)(R - 1) * BB * 1024), BB * 1024 / 2);

    // -------- serial recurrence (merged cell0 || cell1 || Zin), 514 launches --------
    SArgs a;
    a.inp = inputs; a.Sv = Sv; a.SG = SG; a.b0 = b0; a.b1 = b1;
    a.WFh = WFh; a.WFl = WFl; a.W0h = W0h; a.W0l = W0l; a.W1h = W1h; a.W1l = W1l;
    a.h0h0 = h0h0; a.h0l0 = h0l0; a.h0h1 = h0h1; a.h0l1 = h0l1;
    a.ringh = ringh; a.ringl = ringl;
    a.Zin = Zin; a.c0 = c0; a.c1 = c1;
    a.R = R;

    for (int L = -1; L <= TT; ++L) {
        a.t = L;
        k_step<<<256, 256, LDS_BYTES, stream>>>(a);
        if (L >= 1 && (L % R) == 0) {
            int c = L / R - 1;
            k_head1<<<R * 16, 256, LDS_BYTES, stream>>>(ringh, ringl, oWAh, oWAl, ob0, hsh, hsl);
            k_head2<<<R * 4, 256, LDS_BYTES, stream>>>(hsh, hsl, oWBh, oWBl, ob1,
                                                       out + (size_t)c * R * BB * 256);
        }
    }
}